// Round 1
// 273.292 us; speedup vs baseline: 1.0548x; 1.0548x over previous
//
#include <hip/hip_runtime.h>
#include <hip/hip_bf16.h>
#include <hip/hip_fp16.h>

// Problem constants (from setup_inputs): B=4, T=4096, D=1024, H=1024
#define B_ 4
#define T_ 4096
#define D_ 1024
#define H_ 1024
#define M_ (B_ * T_)   // 16384

typedef __attribute__((ext_vector_type(8))) short short8;   // 8 bf16 = 4 VGPRs (MFMA A/B frag)
typedef __attribute__((ext_vector_type(4))) float f32x4;    // MFMA C/D frag

// ---------------- fp32 -> bf16 (RNE) ----------------
__device__ __forceinline__ unsigned short f2bf(float f) {
    unsigned int u = __float_as_uint(f);
    u += 0x7fffu + ((u >> 16) & 1u);
    return (unsigned short)(u >> 16);
}

// One kernel converts x -> xb and Wz/Wh -> interleaved wcb.
// wcb int-row layout: 32-row groups; rows [32a..32a+15] = Wz[16a..16a+15],
// rows [32a+16..32a+31] = Wh[16a..16a+15]. This turns the dual GEMM into a
// single GEMM with N_int=2048 where even/odd 16-col fragments are (z,h) pairs.
__global__ __launch_bounds__(256) void convert_all(
    const float* __restrict__ x, const float* __restrict__ wz, const float* __restrict__ wh,
    unsigned short* __restrict__ xb, unsigned short* __restrict__ wcb)
{
    int i = blockIdx.x * 256 + threadIdx.x;
    const float* s; unsigned short* d; int soff; int doff;
    if (i < 4194304) {
        s = x; d = xb; soff = i; doff = i;
    } else if (i < 4456448) {
        int off = i - 4194304;          // float4 index within Wz
        int j = off >> 8; int k4 = off & 255;   // 256 float4 per row
        int ic = ((j >> 4) << 5) + (j & 15);
        s = wz; d = wcb; soff = off; doff = ic * 256 + k4;
    } else {
        int off = i - 4456448;
        int j = off >> 8; int k4 = off & 255;
        int ic = ((j >> 4) << 5) + 16 + (j & 15);
        s = wh; d = wcb; soff = off; doff = ic * 256 + k4;
    }
    float4 f = ((const float4*)s)[soff];
    ushort4 u;
    u.x = f2bf(f.x); u.y = f2bf(f.y); u.z = f2bf(f.z); u.w = f2bf(f.w);
    ((ushort4*)d)[doff] = u;
}

// async global->LDS, 16B per lane; LDS dest = wave-uniform base + lane*16
__device__ __forceinline__ void async16(const void* g, void* l) {
    __builtin_amdgcn_global_load_lds(
        (__attribute__((address_space(1))) void*)g,
        (__attribute__((address_space(3))) void*)l,
        16, 0, 0);
}

#define BARRIER() do { asm volatile("" ::: "memory"); __builtin_amdgcn_s_barrier(); asm volatile("" ::: "memory"); } while (0)
#define VMW(n)    asm volatile("s_waitcnt vmcnt(" #n ")" ::: "memory")

// ---------------- fused GEMM (8-phase, counted vmcnt) + epilogue + chunk summary ----------
// Tile 256(M) x 256(N_int = 128 real H cols, z/h interleaved). BK=64, 8 waves (2M x 4N).
// LDS: fragment-order subtiles (16 rows x 32 k, lane-ordered => conflict-free ds_read_b128),
// [buf(2)][khalf(2)][subtile(16)][lane(64)] short8 for A and B = 64 KB + 64 KB = 128 KB.
// Half-tile HT = one (A|B, khalf) = 16 subtiles = 16 KB = 2 async16 per wave.
// Issue stream (1 HT/phase, 2 loads/wave): prologue t0*4HT + t1{A0,B0}; then per group g:
//   phA: t(g+1) A-k1 | phB: t(g+1) B-k1 | phC: t(g+2) A-k0 | phD: t(g+2) B-k0
// Counted waits: vmcnt(8) (=4 HT in flight) at end of phB (guards phC reads) and phD
// (guards next phA reads); tail drains 8 -> 4 -> 0. Never vmcnt(0) in steady state.
// Phases: (k-half, m-half) quadrants; 16 MFMA each, setprio(1) around the cluster (T5).
__global__ __launch_bounds__(512, 2) void dual_gemm_kernel(
    const unsigned short* __restrict__ xb,   // [M][D] bf16
    const unsigned short* __restrict__ wcb,  // [2048][D] bf16, z/h interleaved by 16 rows
    const float* __restrict__ bz,
    const float* __restrict__ bh,
    __half2* __restrict__ av16,              // [M][H] half2(a,v)
    float2* __restrict__ chunkAV)            // [64][B][H]
{
    __shared__ short8 ldsA[2 * 2 * 16 * 64]; // 64 KB
    __shared__ short8 ldsB[2 * 2 * 16 * 64]; // 64 KB

    const int tid  = threadIdx.x;
    const int lane = tid & 63;
    const int w    = __builtin_amdgcn_readfirstlane(tid >> 6); // wave id 0..7 (SGPR)
    const int wr   = w >> 2;                 // 0..1  M-half of block
    const int wc   = w & 3;                  // 0..3  N-quarter of block
    const int r16  = lane & 15;
    const int q    = lane >> 4;

    // XCD swizzle: 512 blocks, round-robin XCD = bid%8 -> XCD x owns contiguous
    // mb range [8x, 8x+8), nb fastest => 4 MB A panel stays in its L2.
    const int bid = blockIdx.x;
    const int swz = (bid & 7) * 64 + (bid >> 3);
    const int nb  = swz & 7;                 // int-col block (256 int cols = 128 real)
    const int mb  = swz >> 3;                // 0..63

    // staging: wave w stages subtiles {2w, 2w+1} of every HT.
    // per-lane global source is frag-order permuted (row r16, k-piece q*8); LDS dest linear.
    const int laneoff = r16 * D_ + q * 8;
    const unsigned short* gA = xb  + (size_t)(mb * 256 + 2 * w * 16) * D_ + laneoff;
    const unsigned short* gB = wcb + (size_t)(nb * 256 + 2 * w * 16) * D_ + laneoff;

#define STAGE_A(tt, kh, pp) do { \
    const unsigned short* _s = gA + (tt) * 64 + (kh) * 32; \
    short8* _d = &ldsA[(pp) * 2048 + (kh) * 1024 + 2 * w * 64]; \
    async16(_s, _d); \
    async16(_s + 16 * D_, _d + 64); } while (0)
#define STAGE_B(tt, kh, pp) do { \
    const unsigned short* _s = gB + (tt) * 64 + (kh) * 32; \
    short8* _d = &ldsB[(pp) * 2048 + (kh) * 1024 + 2 * w * 64]; \
    async16(_s, _d); \
    async16(_s + 16 * D_, _d + 64); } while (0)

    f32x4 acc[8][4] = {};

    // prologue: t0 {A-k0, B-k0, A-k1, B-k1}, t1 {A-k0, B-k0}  (12 loads/wave)
    STAGE_A(0, 0, 0); STAGE_B(0, 0, 0);
    STAGE_A(0, 1, 0); STAGE_B(0, 1, 0);
    STAGE_A(1, 0, 1); STAGE_B(1, 0, 1);
    VMW(8);        // t0 A-k0/B-k0 landed
    BARRIER();

    short8 fa[4], fb[4];

#define MFMA16(MH) do { \
    _Pragma("unroll") \
    for (int m = 0; m < 4; ++m) { \
        _Pragma("unroll") \
        for (int n = 0; n < 4; ++n) \
            acc[(MH) * 4 + m][n] = __builtin_amdgcn_mfma_f32_16x16x32_bf16( \
                fa[m], fb[n], acc[(MH) * 4 + m][n], 0, 0, 0); \
    } } while (0)

    for (int g = 0; g < 16; ++g) {
        const int p  = g & 1;
        const int bA = p * 2048;             // wave-uniform (SGPR) LDS bases
        const int oA = bA + wr * 512;
        const int oB = bA + wc * 256;

        // ---- phase A: k-half 0, m-half 0 ----
#pragma unroll
        for (int m = 0; m < 4; ++m) fa[m] = ldsA[oA + m * 64 + lane];
#pragma unroll
        for (int n = 0; n < 4; ++n) fb[n] = ldsB[oB + n * 64 + lane];
        if (g < 15) STAGE_A(g + 1, 1, p ^ 1);
        BARRIER();
        __builtin_amdgcn_s_setprio(1);
        MFMA16(0);
        __builtin_amdgcn_s_setprio(0);
        BARRIER();

        // ---- phase B: k-half 0, m-half 1 (fb reused) ----
#pragma unroll
        for (int m = 0; m < 4; ++m) fa[m] = ldsA[oA + (4 + m) * 64 + lane];
        if (g < 15) STAGE_B(g + 1, 1, p ^ 1);
        BARRIER();
        __builtin_amdgcn_s_setprio(1);
        MFMA16(1);
        __builtin_amdgcn_s_setprio(0);
        if (g < 15) { VMW(8); } else { VMW(0); }   // guard phase C reads (t_g k1)
        BARRIER();

        // ---- phase C: k-half 1, m-half 0 ----
#pragma unroll
        for (int m = 0; m < 4; ++m) fa[m] = ldsA[oA + 1024 + m * 64 + lane];
#pragma unroll
        for (int n = 0; n < 4; ++n) fb[n] = ldsB[oB + 1024 + n * 64 + lane];
        if (g < 14) STAGE_A(g + 2, 0, p);
        BARRIER();
        __builtin_amdgcn_s_setprio(1);
        MFMA16(0);
        __builtin_amdgcn_s_setprio(0);
        BARRIER();

        // ---- phase D: k-half 1, m-half 1 ----
#pragma unroll
        for (int m = 0; m < 4; ++m) fa[m] = ldsA[oA + 1024 + (4 + m) * 64 + lane];
        if (g < 14) STAGE_B(g + 2, 0, p);
        BARRIER();
        __builtin_amdgcn_s_setprio(1);
        MFMA16(1);
        __builtin_amdgcn_s_setprio(0);
        if (g < 14) { VMW(8); } else if (g == 14) { VMW(4); }  // guard next phase A
        BARRIER();
    }

    // ---------------- epilogue ----------------
    // C/D layout: col = lane&15, row = q*4 + rr  [verified m89/m91].
    // acc[mf][2*gg] = z-GEMM, acc[mf][2*gg+1] = h-GEMM for real col
    //   ncol = nb*128 + wc*32 + gg*16 + r16; rows m = mb*256 + wr*128 + mf*16 + q*4 + rr.
    const int mrow0 = mb * 256 + wr * 128;
#pragma unroll
    for (int gg = 0; gg < 2; ++gg) {
        const int ncol = nb * 128 + wc * 32 + gg * 16 + r16;
        const float bzv = bz[ncol];
        const float bhv = bh[ncol];
#pragma unroll
        for (int hh = 0; hh < 2; ++hh) {     // two 64-row chunks per wave
            float CA = 1.0f, CV = 0.0f;
#pragma unroll
            for (int mm = 0; mm < 4; ++mm) {
                const int mf = hh * 4 + mm;
                float LA = 1.0f, LV = 0.0f;  // this lane's 4-row segment
#pragma unroll
                for (int rr = 0; rr < 4; ++rr) {
                    float kv = acc[mf][2 * gg + 0][rr] + bzv;
                    float hv = acc[mf][2 * gg + 1][rr] + bhv;
                    float tk = __expf(-fabsf(kv));
                    float ik = 1.0f / (1.0f + tk);
                    float sig = (kv >= 0.0f) ? ik : tk * ik;         // sigmoid(k)
                    float ac  = (kv >= 0.0f) ? tk * ik : ik;         // sigmoid(-k)
                    float th = __expf(-fabsf(hv));
                    float ih = 1.0f / (1.0f + th);
                    float gh = (hv >= 0.0f) ? (hv + 0.5f) : th * ih; // g(hb)
                    float vv = sig * gh;
                    const size_t m = (size_t)(mrow0 + mf * 16 + q * 4 + rr);
                    av16[m * H_ + ncol] = __floats2half2_rn(ac, vv);
                    LV = ac * LV + vv;       // ascending t composition
                    LA = ac * LA;
                }
                // order-preserving combine across q (lower lane index = earlier rows)
#pragma unroll
                for (int mask = 16; mask <= 32; mask <<= 1) {
                    float PA = __shfl_xor(LA, mask);
                    float PV = __shfl_xor(LV, mask);
                    if (lane & mask) { LV = LA * PV + LV; LA = LA * PA; }
                    else             { LV = PA * LV + PV; LA = PA * LA; }
                }
                CV = LA * CV + LV;
                CA = LA * CA;
            }
            if (q == 0) {
                const int cglob = mb * 4 + wr * 2 + hh;   // global 64-row chunk id 0..255
                chunkAV[(cglob & 63) * 4096 + (cglob >> 6) * 1024 + ncol] = make_float2(CA, CV);
            }
        }
    }
#undef STAGE_A
#undef STAGE_B
#undef MFMA16
}

// ---------------- scan pass2: sequential over 64 chunk summaries per channel ----------------
__global__ __launch_bounds__(256) void scan_pass2(const float2* __restrict__ chunkAV,
                                                  const float* __restrict__ h0,
                                                  float* __restrict__ hstart) {
    int chan = blockIdx.x * blockDim.x + threadIdx.x;   // 4096 threads
    int n = chan & (H_ - 1);
    int b = chan >> 10;
    float x = h0[b * H_ + n];
    float h;
    if (x >= 0.0f) { h = x + 0.5f; }
    else { float t = __expf(x); h = t / (1.0f + t); }   // g(h0)
#pragma unroll 8
    for (int c = 0; c < 64; ++c) {
        hstart[c * 4096 + chan] = h;
        float2 s = chunkAV[c * 4096 + chan];
        h = s.x * h + s.y;
    }
}

// ---------------- scan pass3: replay each chunk from entry state ----------------
__global__ __launch_bounds__(256) void scan_pass3(const __half2* __restrict__ av16,
                                                  const float* __restrict__ hstart,
                                                  float* __restrict__ out) {
    int g = blockIdx.x * blockDim.x + threadIdx.x;
    int n = g & (H_ - 1);
    int rest = g >> 10;
    int c = rest & 63;
    int b = rest >> 6;
    float h = hstart[c * 4096 + b * 1024 + n];
    const __half2* base = av16 + ((size_t)(b * T_ + c * 64)) * H_ + n;
    float* obase = out + ((size_t)(b * T_ + c * 64)) * H_ + n;
#pragma unroll 8
    for (int t = 0; t < 64; ++t) {
        float2 p = __half22float2(base[(size_t)t * H_]);
        h = p.x * h + p.y;
        obase[(size_t)t * H_] = h;
    }
}

// ---------------- launch ----------------
extern "C" void kernel_launch(void* const* d_in, const int* in_sizes, int n_in,
                              void* d_out, int out_size, void* d_ws, size_t ws_size,
                              hipStream_t stream) {
    const float* x  = (const float*)d_in[0];   // [B,T,D]
    const float* h0 = (const float*)d_in[1];   // [B,H]
    const float* Wz = (const float*)d_in[2];   // [H,D]
    const float* bz = (const float*)d_in[3];   // [H]
    const float* Wh = (const float*)d_in[4];   // [H,D]
    const float* bh = (const float*)d_in[5];   // [H]
    float* out = (float*)d_out;

    // workspace layout (bytes):
    //   xb  bf16 [M][D]            @ 0            33,554,432
    //   wcb bf16 [2048][D]         @ 33554432      4,194,304
    //   av16 half2 [M][H]          @ 37748736     67,108,864
    //   chunkAV float2 [64][B][H]  @ 104857600     2,097,152
    //   hstart fp32 [64][B*H]      @ 106954752     1,048,576
    char* ws = (char*)d_ws;
    unsigned short* xb  = (unsigned short*)(ws);
    unsigned short* wcb = (unsigned short*)(ws + 33554432);
    __half2* av16       = (__half2*)(ws + 37748736);
    float2* chunkAV     = (float2*)(ws + 104857600);
    float*  hstart      = (float*)(ws + 106954752);

    convert_all<<<18432, 256, 0, stream>>>(x, Wz, Wh, xb, wcb);

    dual_gemm_kernel<<<512, 512, 0, stream>>>(xb, wcb, bz, bh, av16, chunkAV);

    scan_pass2<<<16,   256, 0, stream>>>(chunkAV, h0, hstart);
    scan_pass3<<<1024, 256, 0, stream>>>(av16, hstart, out);
}